// Round 17
// baseline (40.285 us; speedup 1.0000x reference)
//
#include <hip/hip_runtime.h>

// Problem constants (fixed by setup_inputs).
#define B_     16
#define C_     3
#define H_     512
#define W_     1024
#define MW     256         // mask_width
#define RS     16          // output rows per strip
#define NSTRIP 32          // 32*16 = 512 exact (no ragged strip)
#define NIN    (RS + 10)   // 26 input rows streamed per strip
#define NBLK   (B_ * C_ * NSTRIP)  // 1536

// Memory fence only: wave_barrier pins all DS/VMEM ordering (IR + MIR) but
// lets pure VALU flow across iterations (software pipelining).
#define FENCE() __builtin_amdgcn_wave_barrier()

__global__ __launch_bounds__(256) void ssim_main(const float* __restrict__ img1,
                                                 const float* __restrict__ img2,
                                                 const int*   __restrict__ mask_pos,
                                                 float*       __restrict__ partials) {
    // Gaussian weights = float64 exp/normalize, precomputed to float literals.
    constexpr float G[11] = {
        0.00102838f, 0.00759876f, 0.03600077f, 0.10936070f, 0.21300553f,
        0.26601173f, 0.21300553f, 0.10936070f, 0.03600077f, 0.00759876f,
        0.00102838f };

    // Per-wave double-buffered 74-col {u=x+y, v=x-y} row ring. ~5 KB total.
    // Row i lives in LDS buf (i&1); buf index is COMPILE-TIME under unroll-12.
    __shared__ float2 rowbuf[4][2][80];
    __shared__ float  blksum[4];

    const int tid  = threadIdx.x;
    const int w    = tid >> 6;
    const int lane = tid & 63;

    // L2-locality remap: 8 XCDs x 6 images x 32 strips (bijection, 1536).
    const int d     = blockIdx.x;
    const int xcd   = d & 7;
    const int q     = d >> 3;            // 0..191 within XCD
    const int bc    = xcd * 6 + (q >> 5);// (b,ch) 0..47
    const int strip = q & 31;            // row strip 0..31
    const int b     = bc / 3;

    int s0 = mask_pos[b];
    s0 = min(max(s0, 0), W_ - MW);

    const float* __restrict__ p1 = img1 + (size_t)bc * (H_ * W_);
    const float* __restrict__ p2 = img2 + (size_t)bc * (H_ * W_);

    const int y0  = strip * RS;
    const int sx0 = w << 6;              // column strip base within crop
    const int cxm = sx0 - 5 + lane;      // main staged column (crop coords)
    const int cxh = sx0 + 59 + lane;     // halo staged column (lane < 10)
    const bool vm = (cxm >= 0) && (cxm < MW);
    const bool vh = (lane < 10) && (cxh < MW);
    const int gxm = s0 + cxm;
    const int gxh = s0 + cxh;

    // TWO named prefetch register sets, DISTANCE-2 pipeline:
    //   row r: loaded into set (r&1) at iter r-2; ds_written to LDS buf (r&1)
    //   at iter r-1; read from LDS at iter r.
    // The ds_write at iter i uses the set loaded at iter i-1 while the 4 loads
    // issued THIS iter are newer -> compiler emits a counted vmcnt(4), giving
    // ~2 iteration bodies of HBM-latency cover (vs ~1 body at distance 1).
    float Aa0, Ab0, Aa1, Ab1;            // set A: even rows -> LDS buf 0
    float Ba0, Bb0, Ba1, Bb1;            // set B: odd rows  -> LDS buf 1

    auto loadA = [&](int r) {
        Aa0 = Ab0 = Aa1 = Ab1 = 0.f;
        if (r >= 0 && r < H_) {          // wave-uniform branch
            const int ro = r * W_;
            if (vm) { Aa0 = p1[ro + gxm]; Ab0 = p2[ro + gxm]; }
            if (vh) { Aa1 = p1[ro + gxh]; Ab1 = p2[ro + gxh]; }
        }
    };
    auto loadB = [&](int r) {
        Ba0 = Bb0 = Ba1 = Bb1 = 0.f;
        if (r >= 0 && r < H_) {
            const int ro = r * W_;
            if (vm) { Ba0 = p1[ro + gxm]; Bb0 = p2[ro + gxm]; }
            if (vh) { Ba1 = p1[ro + gxh]; Bb1 = p2[ro + gxh]; }
        }
    };
    // u/v transform INLINE at the store (round-8 lesson: first use of the
    // loads — and thus the vmcnt wait — belongs at the ds_write).
    auto storeA = [&]() {                // even rows -> LDS buf 0
        rowbuf[w][0][lane] = make_float2(Aa0 + Ab0, Aa0 - Ab0);
        if (lane < 10) rowbuf[w][0][64 + lane] = make_float2(Aa1 + Ab1, Aa1 - Ab1);
    };
    auto storeB = [&]() {                // odd rows -> LDS buf 1
        rowbuf[w][1][lane] = make_float2(Ba0 + Bb0, Ba0 - Bb0);
        if (lane < 10) rowbuf[w][1][64 + lane] = make_float2(Ba1 + Bb1, Ba1 - Bb1);
    };

    // 12-slot accumulator ring x 4 fields {mu_p, mu_m, Suu, Svv}.
    // Output row o lives in slot o%12; 12 slots (not 11) make BOTH the slot
    // index and the row parity compile-time at unroll depth 12 (the proven
    // safe depth — unroll-22 variants spilled in rounds 4/6/12). Slot
    // (j+2)%12 is reset each iter and idles one iter before reuse.
    // SCATTER-RMW form is load-bearing for regalloc (round 13).
    float acc[12][4];
    #pragma unroll
    for (int s = 0; s < 12; ++s)
        #pragma unroll
        for (int f = 0; f < 4; ++f) acc[s][f] = 0.f;

    float psum = 0.f;

    auto dorow = [&](int i, int j) {     // j == i%12, compile-time
        const int par = j & 1;           // row i parity == LDS buf index

        // Issue loads for row i+2 into set par (its old row-i contents were
        // ds_written at iter i-1 -> registers free).
        if (i + 2 < NIN) {
            if (par == 0) loadA(y0 - 3 + i);   // (y0-5) + (i+2)
            else          loadB(y0 - 3 + i);
        }

        // Horizontal 11-tap pass over 4 fields from LDS buf par (row i).
        float su = 0.f, sv = 0.f, suu = 0.f, svv = 0.f;
        #pragma unroll
        for (int t = 0; t < 11; ++t) {
            const float2 q2 = rowbuf[w][par][lane + t];
            const float gu = G[t] * q2.x;
            const float gv = G[t] * q2.y;
            su += gu;
            sv += gv;
            suu = fmaf(gu, q2.x, suu);
            svv = fmaf(gv, q2.y, svv);
        }

        // Vertical scatter: output o = i-10+m (slot o%12 = (j+2+m)%12) gets
        // weight G[10-m] from this row. All slot indices compile-time.
        #pragma unroll
        for (int m = 0; m < 11; ++m) {
            const int s = (j + 2 + m) % 12;
            const float gw = G[10 - m];
            acc[s][0] = fmaf(gw, su,  acc[s][0]);
            acc[s][1] = fmaf(gw, sv,  acc[s][1]);
            acc[s][2] = fmaf(gw, suu, acc[s][2]);
            acc[s][3] = fmaf(gw, svv, acc[s][3]);
        }

        // Output o = i-10 completes in slot (j+2)%12 at i >= 10.
        {
            const int so = (j + 2) % 12;
            if (i >= 10) {
                const float mup = acc[so][0], mum = acc[so][1];
                const float Suu = acc[so][2], Svv = acc[so][3];
                const float A  = mup * mup, Bq = mum * mum;
                const float mu_sq_sum = 0.5f * (A + Bq);    // mu1^2 + mu2^2
                const float mu_cross2 = 0.5f * (A - Bq);    // 2*mu1*mu2
                const float e_sum     = 0.5f * (Suu + Svv); // Exx + Eyy
                const float e_cross2  = 0.5f * (Suu - Svv); // 2*Exy
                const float sig_sum = e_sum - mu_sq_sum;    // sig1 + sig2
                const float sig12_2 = e_cross2 - mu_cross2; // 2*sig12
                const float num = (mu_cross2 + 1e-4f) * (sig12_2 + 9e-4f) + 1e-5f;
                const float den = (mu_sq_sum + 1e-4f) * (sig_sum + 9e-4f) + 1e-5f;
                psum += __fdividef(num, den);
            }
            // Always reset (clears pre-window garbage for i<10; recycles the
            // slot for output o+12, whose first write is at iter i+2).
            #pragma unroll
            for (int f = 0; f < 4; ++f) acc[so][f] = 0.f;
        }

        // ds_write row i+1 (set par^1, loaded at iter i-1) into buf par^1.
        // The automatic waitcnt here is vmcnt(4): only the OLDER set drains.
        if (i + 1 < NIN) {
            if (par == 0) storeB();
            else          storeA();
        }
        // Memory-only fence: DS/VMEM may not cross; VALU may.
        FENCE();
    };

    // Prologue: row 0 -> set A -> LDS buf 0; row 1 -> set B (stays in regs).
    loadA(y0 - 5);
    loadB(y0 - 4);
    storeA();
    FENCE();

    // Main 24 rows (2 x 12: slot and parity compile-time at proven unroll
    // depth), then 2-row tail (24%12 == 0, so tail j = 0,1).
    for (int ii = 0; ii < 24; ii += 12) {
        #pragma unroll
        for (int j = 0; j < 12; ++j) dorow(ii + j, j);
    }
    dorow(24, 0);
    dorow(25, 1);

    // Wave reduce -> block reduce -> one plain store per block (no atomic,
    // no zeroing: every slot written every run).
    #pragma unroll
    for (int off = 32; off > 0; off >>= 1) psum += __shfl_xor(psum, off, 64);
    if (lane == 0) blksum[w] = psum;
    __syncthreads();
    if (tid == 0) {
        partials[d] = blksum[0] + blksum[1] + blksum[2] + blksum[3];
    }
}

__global__ __launch_bounds__(256) void ssim_final(const float* __restrict__ partials,
                                                  float* __restrict__ out) {
    __shared__ float red[4];
    const int t = threadIdx.x;
    float s = 0.f;
    #pragma unroll
    for (int k = 0; k < NBLK / 256; ++k) s += partials[t + 256 * k];
    #pragma unroll
    for (int off = 32; off > 0; off >>= 1) s += __shfl_xor(s, off, 64);
    if ((t & 63) == 0) red[t >> 6] = s;
    __syncthreads();
    if (t == 0)
        out[0] = 1.0f - (red[0] + red[1] + red[2] + red[3]) * (1.0f / 6291456.0f);
}

extern "C" void kernel_launch(void* const* d_in, const int* in_sizes, int n_in,
                              void* d_out, int out_size, void* d_ws, size_t ws_size,
                              hipStream_t stream) {
    const float* img1 = (const float*)d_in[0];
    const float* img2 = (const float*)d_in[1];
    const int*   pos  = (const int*)d_in[2];
    float* out      = (float*)d_out;
    float* partials = (float*)d_ws;      // NBLK floats = 6 KB scratch

    // No memset: every partials slot is unconditionally written by ssim_main.
    // 8 XCDs x 6 images x 32 strips; each block = 4 waves = 4 column strips.
    ssim_main<<<NBLK, 256, 0, stream>>>(img1, img2, pos, partials);
    ssim_final<<<1, 256, 0, stream>>>(partials, out);
}